// Round 8
// baseline (321.619 us; speedup 1.0000x reference)
//
#include <hip/hip_runtime.h>
#include <math.h>

typedef short s16x8 __attribute__((ext_vector_type(8)));
typedef short s16x4 __attribute__((ext_vector_type(4)));
typedef float f32x4 __attribute__((ext_vector_type(4)));

#define MFMA(a, b, c)    __builtin_amdgcn_mfma_f32_16x16x32_bf16(a, b, c, 0, 0, 0)
#define MFMA16(a, b, c)  __builtin_amdgcn_mfma_f32_16x16x16bf16_1k(a, b, c, 0, 0, 0)

__device__ __forceinline__ float b2f(ushort u) {
    union { unsigned int i; float f; } v; v.i = ((unsigned int)u) << 16; return v.f;
}
__device__ __forceinline__ ushort f2b(float f) {
    union { float f; unsigned int i; } v; v.f = f;
    unsigned int r = v.i + 0x7fffu + ((v.i >> 16) & 1u);
    return (ushort)(r >> 16);
}
__device__ __forceinline__ float gelu_tanh(float v) {
    float u = 0.7978845608f * (v + 0.044715f * v * v * v);
    float e = __expf(-2.f * fabsf(u));
    float t = (1.f - e) / (1.f + e);            // tanh(|u|)
    t = (u < 0.f) ? -t : t;
    return 0.5f * v * (1.f + t);
}

// ---------------------------------------------------------------------------
// K0: all prep. blocks [0,192): qkv_w->wq; [192,256): proj_w->wp;
// [256,768): fc1/fc2->wf; [768,832): bias+mask table bm[cls][head][128][128].
// ---------------------------------------------------------------------------
__global__ __launch_bounds__(256) void k0_prep(
    const float* __restrict__ qkv_w, const float* __restrict__ proj_w,
    const float* __restrict__ fc1_w, const float* __restrict__ fc2_w,
    const float* __restrict__ rpb, ushort* __restrict__ wq,
    ushort* __restrict__ wp, ushort* __restrict__ wf, ushort* __restrict__ bm)
{
    int bid = blockIdx.x, tid = threadIdx.x;
    if (bid < 192) { int idx = bid * 256 + tid; wq[idx] = f2b(qkv_w[idx]); return; }
    if (bid < 256) { int idx = (bid - 192) * 256 + tid; wp[idx] = f2b(proj_w[idx]); return; }
    if (bid < 768) {
        int idx = (bid - 256) * 256 + tid;
        wf[idx] = f2b(idx < 65536 ? fc1_w[idx] : fc2_w[idx - 65536]);
        return;
    }
    int bi = bid - 768;                             // [0,64) = cls*8+head
    int cls = bi >> 3, head = bi & 7;
    int ed = (cls >> 2) & 1, eh = (cls >> 1) & 1, ew = cls & 1;
    int j = tid & 127;
    int tdj = j >> 6, thj = (j >> 3) & 7, twj = j & 7;
    int regj = (ed ? (tdj + 1) : 0) * 9
             + (eh ? ((thj < 4) ? 1 : 2) : 0) * 3
             + (ew ? ((twj < 4) ? 1 : 2) : 0);
    ushort* bmp = bm + (long)bi * 16384;
    for (int ii = 0; ii < 64; ++ii) {
        int i = (tid >> 7) * 64 + ii;
        int tdi = i >> 6, thi = (i >> 3) & 7, twi = i & 7;
        int regi = (ed ? (tdi + 1) : 0) * 9
                 + (eh ? ((thi < 4) ? 1 : 2) : 0) * 3
                 + (ew ? ((twi < 4) ? 1 : 2) : 0);
        int rpi = (tdi - tdj + 1) * 225 + (thi - thj + 7) * 15 + (twi - twj + 7);
        float v = rpb[rpi * 8 + head] + ((regi != regj) ? -100.f : 0.f);
        bmp[i * 128 + j] = f2b(v);
    }
}

// ---------------------------------------------------------------------------
// K23 (unchanged from R7): one block per WINDOW, 512 threads = 8 waves.
// Phase A: LN1+shift+gather (4 thr/row). Phase B: QKV GEMM 4m x 2n.
// Phase C: 1 head per wave, R5-verified swapped-QK^T register softmax.
// O -> obuf [wi][head][tok][16].
// ---------------------------------------------------------------------------
__global__ __launch_bounds__(512) void k23(
    const float* __restrict__ x, const float* __restrict__ g,
    const float* __restrict__ be, const ushort* __restrict__ wq,
    const float* __restrict__ qkv_b, const ushort* __restrict__ bm,
    ushort* __restrict__ obuf)
{
    __shared__ __align__(16) ushort As[128][136];   // LN1 out; later V^T [h][16][136]
    __shared__ __align__(16) ushort qb[128][132];   // Q [tok][128ch]
    __shared__ __align__(16) ushort kb[128][132];   // K [tok][128ch]
    int tid = threadIdx.x;
    int wi = blockIdx.x;
    int wd = (wi >> 6) & 3, wh = (wi >> 3) & 7, ww = wi & 7;
    int cls = ((wd == 3) << 2) | ((wh == 7) << 1) | (ww == 7);
    {   // Phase A: LN + shift + gather -> As (4 threads per row)
        int row = tid >> 2, part = tid & 3;
        int b = wi >> 8;
        int td = row >> 6, th = (row >> 3) & 7, tw = row & 7;
        int d = (wd * 2 + td + 1) & 7;
        int h = (wh * 8 + th + 4) & 63;
        int w = (ww * 8 + tw + 4) & 63;
        long src = (((long)((b * 8 + d) * 64 + h)) * 64 + w) * 128 + part * 32;
        float vals[32];
        float s = 0.f, q = 0.f;
        #pragma unroll
        for (int i = 0; i < 8; ++i) {
            float4 u = *(const float4*)&x[src + i * 4];
            vals[i * 4 + 0] = u.x; vals[i * 4 + 1] = u.y;
            vals[i * 4 + 2] = u.z; vals[i * 4 + 3] = u.w;
            s += u.x + u.y + u.z + u.w;
            q += u.x * u.x + u.y * u.y + u.z * u.z + u.w * u.w;
        }
        s += __shfl_xor(s, 1); s += __shfl_xor(s, 2);
        q += __shfl_xor(q, 1); q += __shfl_xor(q, 2);
        float mean = s * (1.f / 128.f);
        float rstd = rsqrtf(q * (1.f / 128.f) - mean * mean + 1e-5f);
        #pragma unroll
        for (int i = 0; i < 4; ++i) {
            ushort pk[8];
            #pragma unroll
            for (int jj = 0; jj < 8; ++jj) {
                int c = part * 32 + i * 8 + jj;
                pk[jj] = f2b((vals[i * 8 + jj] - mean) * rstd * g[c] + be[c]);
            }
            *(uint4*)&As[row][part * 32 + i * 8] = *(uint4*)pk;
        }
    }
    __syncthreads();
    int wv = tid >> 6, lane = tid & 63, li = lane & 15, quad = lane >> 4;
    int wm = wv >> 1, wn = wv & 1;                  // wm 0..3, wn 0..1
    // Phase B: QKV GEMM -> LDS (q->qb, k->kb, v^T->As region)
    for (int nb = 0; nb < 3; ++nb) {
        f32x4 acc[2][4] = {};
        for (int s = 0; s < 4; ++s) {
            s16x8 a[2], bw[4];
            #pragma unroll
            for (int mi = 0; mi < 2; ++mi)
                a[mi] = *(const s16x8*)&As[wm * 32 + mi * 16 + li][s * 32 + quad * 8];
            #pragma unroll
            for (int ni = 0; ni < 4; ++ni)
                bw[ni] = *(const s16x8*)&wq[(long)(nb * 128 + wn * 64 + ni * 16 + li) * 128
                                            + s * 32 + quad * 8];
            #pragma unroll
            for (int mi = 0; mi < 2; ++mi)
                #pragma unroll
                for (int ni = 0; ni < 4; ++ni)
                    acc[mi][ni] = MFMA(a[mi], bw[ni], acc[mi][ni]);
        }
        if (nb == 2) __syncthreads();   // all As (A-operand) reads done before V^T overwrite
        #pragma unroll
        for (int mi = 0; mi < 2; ++mi)
            #pragma unroll
            for (int ni = 0; ni < 4; ++ni) {
                int gcol = nb * 128 + wn * 64 + ni * 16 + li;
                float bias = qkv_b[gcol];
                float scale = (nb == 0) ? 0.25f : 1.f;   // SCALE = 16^-0.5
                #pragma unroll
                for (int r = 0; r < 4; ++r) {
                    int trow = wm * 32 + mi * 16 + quad * 4 + r;
                    ushort val = f2b((acc[mi][ni][r] + bias) * scale);
                    if (nb == 0) {
                        qb[trow][gcol] = val;
                    } else if (nb == 1) {
                        kb[trow][gcol - 128] = val;
                    } else {
                        int c2 = gcol - 256, hh = c2 >> 4, dd = c2 & 15;
                        ((ushort*)As)[hh * 2176 + dd * 136 + trow] = val;  // V^T [h][d][tok]
                    }
                }
            }
    }
    __syncthreads();
    // Phase C: attention (R5-verified math), wave wv = head wv.
    const ushort* vtp = (const ushort*)As;
    {
        int h = wv;
        long bmb = (long)(cls * 8 + h) * 16384;
        long ob = (long)wi * 16384 + h * 2048;
        for (int qq = 0; qq < 4; ++qq) {
            int row0 = qq * 32;
            s16x4 qf0 = *(const s16x4*)&qb[row0 + li][h * 16 + quad * 4];
            s16x4 qf1 = *(const s16x4*)&qb[row0 + 16 + li][h * 16 + quad * 4];
            float ps0 = 0.f, ps1 = 0.f;
            uint pa0[8][2], pa1[8][2];
            #pragma unroll
            for (int mi = 0; mi < 8; ++mi) {
                s16x4 kf = *(const s16x4*)&kb[mi * 16 + li][h * 16 + quad * 4];
                f32x4 z = {0.f, 0.f, 0.f, 0.f};
                f32x4 s0 = MFMA16(kf, qf0, z);
                f32x4 s1 = MFMA16(kf, qf1, z);
                s16x4 b0 = *(const s16x4*)&bm[bmb + (row0 + li) * 128 + mi * 16 + quad * 4];
                s16x4 b1 = *(const s16x4*)&bm[bmb + (row0 + 16 + li) * 128 + mi * 16 + quad * 4];
                float e0 = __expf(s0[0] + b2f((ushort)b0[0]));
                float e1 = __expf(s0[1] + b2f((ushort)b0[1]));
                float e2 = __expf(s0[2] + b2f((ushort)b0[2]));
                float e3 = __expf(s0[3] + b2f((ushort)b0[3]));
                ps0 += (e0 + e1) + (e2 + e3);
                pa0[mi][0] = (uint)f2b(e0) | ((uint)f2b(e1) << 16);
                pa0[mi][1] = (uint)f2b(e2) | ((uint)f2b(e3) << 16);
                float f0 = __expf(s1[0] + b2f((ushort)b1[0]));
                float f1 = __expf(s1[1] + b2f((ushort)b1[1]));
                float f2 = __expf(s1[2] + b2f((ushort)b1[2]));
                float f3 = __expf(s1[3] + b2f((ushort)b1[3]));
                ps1 += (f0 + f1) + (f2 + f3);
                pa1[mi][0] = (uint)f2b(f0) | ((uint)f2b(f1) << 16);
                pa1[mi][1] = (uint)f2b(f2) | ((uint)f2b(f3) << 16);
            }
            ps0 += __shfl_xor(ps0, 16); ps0 += __shfl_xor(ps0, 32);
            ps1 += __shfl_xor(ps1, 16); ps1 += __shfl_xor(ps1, 32);
            float inv0 = 1.f / ps0, inv1 = 1.f / ps1;
            f32x4 pc0 = {0.f, 0.f, 0.f, 0.f}, pc1 = {0.f, 0.f, 0.f, 0.f};
            #pragma unroll
            for (int mi = 0; mi < 8; ++mi) {
                s16x4 vf = *(const s16x4*)&vtp[h * 2176 + li * 136 + mi * 16 + quad * 4];
                union { uint2 u; s16x4 v; } a0, a1;
                a0.u.x = pa0[mi][0]; a0.u.y = pa0[mi][1];
                a1.u.x = pa1[mi][0]; a1.u.y = pa1[mi][1];
                pc0 = MFMA16(a0.v, vf, pc0);
                pc1 = MFMA16(a1.v, vf, pc1);
            }
            #pragma unroll
            for (int r = 0; r < 4; ++r) {
                float oi0 = __shfl(inv0, quad * 4 + r);
                float oi1 = __shfl(inv1, quad * 4 + r);
                int i0 = row0 + quad * 4 + r;
                int i1 = row0 + 16 + quad * 4 + r;
                obuf[ob + (long)i0 * 16 + li] = f2b(pc0[r] * oi0);
                obuf[ob + (long)i1 * 16 + li] = f2b(pc1[r] * oi1);
            }
        }
    }
}

// ---------------------------------------------------------------------------
// K45 (R8): 32-token tile, 2048 blocks x 256 threads. Per-wave output 16x64:
// acc/hacc/yacc shrink to f32x4[4] (16 AGPR each, -64 vs 64-tok tile) and
// LDS drops to 27.4KB (~5 blocks/CU static). More, smaller blocks = more
// independent streams per CU to hide L2/exp latency; smaller tail.
// Identical math; LN2 uses 8 partials/row.
// ---------------------------------------------------------------------------
__global__ __launch_bounds__(256) void k45(
    const ushort* __restrict__ ao, const ushort* __restrict__ wp,
    const float* __restrict__ proj_b, const float* __restrict__ x,
    const float* __restrict__ g2, const float* __restrict__ be2,
    const ushort* __restrict__ wf1, const float* __restrict__ fc1_b,
    const ushort* __restrict__ wf2, const float* __restrict__ fc2_b,
    float* __restrict__ out)
{
    __shared__ __align__(16) ushort As[32][132];    // ao tile, later xs (LN2 out)
    __shared__ __align__(16) ushort x1t[32][132];   // x1 (bf16)
    __shared__ __align__(16) ushort hs[32][132];    // gelu(h) chunk
    __shared__ float redS[8][32];
    __shared__ float redQ[8][32];
    int tid = threadIdx.x;
    int b = blockIdx.x;
    int wi = b >> 2, q4 = b & 3;
    int wd = (wi >> 6) & 3, wh = (wi >> 3) & 7, ww = wi & 7;
    int bb = wi >> 8;
    long aob = (long)wi * 16384;
    int tok0 = q4 * 32;
    #pragma unroll
    for (int i = 0; i < 2; ++i) {
        int slot = tid + i * 256;               // 0..511
        int row = slot & 31, hsl = slot >> 5;   // hsl = head*2 + (d-half)
        *(uint4*)&As[row][hsl * 8] =
            *(const uint4*)&ao[aob + (hsl >> 1) * 2048 + (long)(tok0 + row) * 16 + (hsl & 1) * 8];
    }
    __syncthreads();
    int wv = tid >> 6, lane = tid & 63, li = lane & 15, quad = lane >> 4;
    int wm = wv >> 1, wn = wv & 1;              // wm 0..1 (16 rows), wn 0..1 (64 cols)
    f32x4 acc[4] = {};
    for (int s = 0; s < 4; ++s) {
        s16x8 a = *(const s16x8*)&As[wm * 16 + li][s * 32 + quad * 8];
        s16x8 bw[4];
        #pragma unroll
        for (int ni = 0; ni < 4; ++ni)
            bw[ni] = *(const s16x8*)&wp[(long)(wn * 64 + ni * 16 + li) * 128 + s * 32 + quad * 8];
        #pragma unroll
        for (int ni = 0; ni < 4; ++ni)
            acc[ni] = MFMA(a, bw[ni], acc[ni]);
    }
    // epilogue: residual add (f32 x) -> x1t (bf16)
    #pragma unroll
    for (int r = 0; r < 4; ++r) {
        int lrow = wm * 16 + quad * 4 + r;
        int t = tok0 + lrow;
        int td = t >> 6, th = (t >> 3) & 7, tw = t & 7;
        int d = (wd * 2 + td + 1) & 7, h = (wh * 8 + th + 4) & 63, w = (ww * 8 + tw + 4) & 63;
        long di = (((long)((bb * 8 + d) * 64 + h)) * 64 + w) * 128;
        #pragma unroll
        for (int ni = 0; ni < 4; ++ni) {
            int col = wn * 64 + ni * 16 + li;
            x1t[lrow][col] = f2b(acc[ni][r] + proj_b[col] + x[di + col]);
        }
    }
    __syncthreads();
    {   // LN2 from x1t -> xs (reuse As); 8 threads per row
        int token = tid & 31, part = tid >> 5;
        float vals[16];
        float s = 0.f, q = 0.f;
        #pragma unroll
        for (int i = 0; i < 2; ++i) {
            uint4 u = *(const uint4*)&x1t[token][part * 16 + i * 8];
            const ushort* p = (const ushort*)&u;
            #pragma unroll
            for (int j = 0; j < 8; ++j) { float f = b2f(p[j]); vals[i * 8 + j] = f; s += f; q += f * f; }
        }
        redS[part][token] = s; redQ[part][token] = q;
        __syncthreads();
        float st = 0.f, qt = 0.f;
        #pragma unroll
        for (int p2 = 0; p2 < 8; ++p2) { st += redS[p2][token]; qt += redQ[p2][token]; }
        float mean = st * (1.f / 128.f);
        float rstd = rsqrtf(qt * (1.f / 128.f) - mean * mean + 1e-5f);
        #pragma unroll
        for (int i = 0; i < 2; ++i) {
            ushort packed[8];
            #pragma unroll
            for (int j = 0; j < 8; ++j) {
                int c = part * 16 + i * 8 + j;
                packed[j] = f2b((vals[i * 8 + j] - mean) * rstd * g2[c] + be2[c]);
            }
            *(uint4*)&As[token][part * 16 + i * 8] = *(uint4*)packed;
        }
    }
    __syncthreads();
    f32x4 yacc[4] = {};
    for (int hc = 0; hc < 4; ++hc) {
        f32x4 hacc[4] = {};
        #pragma unroll
        for (int kk = 0; kk < 4; ++kk) {
            s16x8 a = *(const s16x8*)&As[wm * 16 + li][kk * 32 + quad * 8];
            s16x8 bw[4];
            #pragma unroll
            for (int ni = 0; ni < 4; ++ni)
                bw[ni] = *(const s16x8*)&wf1[(long)(hc * 128 + wn * 64 + ni * 16 + li) * 128
                                             + kk * 32 + quad * 8];
            #pragma unroll
            for (int ni = 0; ni < 4; ++ni)
                hacc[ni] = MFMA(a, bw[ni], hacc[ni]);
        }
        #pragma unroll
        for (int ni = 0; ni < 4; ++ni) {
            int col = wn * 64 + ni * 16 + li;
            float bbv = fc1_b[hc * 128 + col];
            #pragma unroll
            for (int r = 0; r < 4; ++r) {
                int row = wm * 16 + quad * 4 + r;
                hs[row][col] = f2b(gelu_tanh(hacc[ni][r] + bbv));
            }
        }
        __syncthreads();
        #pragma unroll
        for (int kk = 0; kk < 4; ++kk) {
            s16x8 a = *(const s16x8*)&hs[wm * 16 + li][kk * 32 + quad * 8];
            s16x8 bw[4];
            #pragma unroll
            for (int ni = 0; ni < 4; ++ni)
                bw[ni] = *(const s16x8*)&wf2[(long)(wn * 64 + ni * 16 + li) * 512
                                             + hc * 128 + kk * 32 + quad * 8];
            #pragma unroll
            for (int ni = 0; ni < 4; ++ni)
                yacc[ni] = MFMA(a, bw[ni], yacc[ni]);
        }
        __syncthreads();
    }
    #pragma unroll
    for (int r = 0; r < 4; ++r) {
        int lrow = wm * 16 + quad * 4 + r;
        int t = tok0 + lrow;
        int td = t >> 6, th = (t >> 3) & 7, tw = t & 7;
        int d = (wd * 2 + td + 1) & 7, h = (wh * 8 + th + 4) & 63, w = (ww * 8 + tw + 4) & 63;
        long di = (((long)((bb * 8 + d) * 64 + h)) * 64 + w) * 128;
        #pragma unroll
        for (int ni = 0; ni < 4; ++ni) {
            int col = wn * 64 + ni * 16 + li;
            out[di + col] = b2f(x1t[lrow][col]) + yacc[ni][r] + fc2_b[col];
        }
    }
}

// ---------------------------------------------------------------------------
// ws layout:
//   [0 .. 16.8MB): obuf = attn-out, [wi][head][tok][16] (window stride 16384).
//   tail (fixed offsets, unchanged): wq 96KB | wp 32KB | wf 256KB | bm 2MB.
// d_out holds ONLY the final f32 output (no scratch -> no races).
// ---------------------------------------------------------------------------
extern "C" void kernel_launch(void* const* d_in, const int* in_sizes, int n_in,
                              void* d_out, int out_size, void* d_ws, size_t ws_size,
                              hipStream_t stream)
{
    (void)in_sizes; (void)n_in; (void)out_size; (void)ws_size;
    const float* x      = (const float*)d_in[0];
    const float* qkv_w  = (const float*)d_in[1];
    const float* qkv_b  = (const float*)d_in[2];
    const float* proj_w = (const float*)d_in[3];
    const float* proj_b = (const float*)d_in[4];
    const float* rpb    = (const float*)d_in[5];
    const float* ln1_g  = (const float*)d_in[6];
    const float* ln1_b  = (const float*)d_in[7];
    const float* ln2_g  = (const float*)d_in[8];
    const float* ln2_b  = (const float*)d_in[9];
    const float* fc1_w  = (const float*)d_in[10];
    const float* fc1_b  = (const float*)d_in[11];
    const float* fc2_w  = (const float*)d_in[12];
    const float* fc2_b  = (const float*)d_in[13];
    float* out = (float*)d_out;

    ushort* obuf = (ushort*)d_ws;                       // 16.8 MB used
    ushort* wq   = (ushort*)((char*)d_ws + 50331648);   // 49152 elems
    ushort* wp   = wq + 49152;                          // 16384
    ushort* wf   = wp + 16384;                          // 131072
    ushort* bm   = wf + 131072;                         // 1048576

    hipLaunchKernelGGL(k0_prep, dim3(832), dim3(256), 0, stream,
                       qkv_w, proj_w, fc1_w, fc2_w, rpb, wq, wp, wf, bm);
    hipLaunchKernelGGL(k23, dim3(512), dim3(512), 0, stream,
                       x, ln1_g, ln1_b, wq, qkv_b, bm, obuf);
    hipLaunchKernelGGL(k45, dim3(2048), dim3(256), 0, stream,
                       obuf, wp, proj_b, x, ln2_g, ln2_b,
                       wf, fc1_b, wf + 65536, fc2_b, out);
}

// Round 9
// 274.559 us; speedup vs baseline: 1.1714x; 1.1714x over previous
//
#include <hip/hip_runtime.h>
#include <math.h>

typedef short s16x8 __attribute__((ext_vector_type(8)));
typedef short s16x4 __attribute__((ext_vector_type(4)));
typedef float f32x4 __attribute__((ext_vector_type(4)));

#define MFMA(a, b, c)    __builtin_amdgcn_mfma_f32_16x16x32_bf16(a, b, c, 0, 0, 0)
#define MFMA16(a, b, c)  __builtin_amdgcn_mfma_f32_16x16x16bf16_1k(a, b, c, 0, 0, 0)

__device__ __forceinline__ float b2f(ushort u) {
    union { unsigned int i; float f; } v; v.i = ((unsigned int)u) << 16; return v.f;
}
__device__ __forceinline__ ushort f2b(float f) {
    union { float f; unsigned int i; } v; v.f = f;
    unsigned int r = v.i + 0x7fffu + ((v.i >> 16) & 1u);
    return (ushort)(r >> 16);
}
__device__ __forceinline__ float gelu_tanh(float v) {
    float u = 0.7978845608f * (v + 0.044715f * v * v * v);
    float e = __expf(-2.f * fabsf(u));
    float t = (1.f - e) / (1.f + e);            // tanh(|u|)
    t = (u < 0.f) ? -t : t;
    return 0.5f * v * (1.f + t);
}

// ---------------------------------------------------------------------------
// K0: all prep. blocks [0,192): qkv_w->wq; [192,256): proj_w->wp;
// [256,768): fc1/fc2->wf; [768,832): bias+mask table bm[cls][head][128][128].
// ---------------------------------------------------------------------------
__global__ __launch_bounds__(256) void k0_prep(
    const float* __restrict__ qkv_w, const float* __restrict__ proj_w,
    const float* __restrict__ fc1_w, const float* __restrict__ fc2_w,
    const float* __restrict__ rpb, ushort* __restrict__ wq,
    ushort* __restrict__ wp, ushort* __restrict__ wf, ushort* __restrict__ bm)
{
    int bid = blockIdx.x, tid = threadIdx.x;
    if (bid < 192) { int idx = bid * 256 + tid; wq[idx] = f2b(qkv_w[idx]); return; }
    if (bid < 256) { int idx = (bid - 192) * 256 + tid; wp[idx] = f2b(proj_w[idx]); return; }
    if (bid < 768) {
        int idx = (bid - 256) * 256 + tid;
        wf[idx] = f2b(idx < 65536 ? fc1_w[idx] : fc2_w[idx - 65536]);
        return;
    }
    int bi = bid - 768;                             // [0,64) = cls*8+head
    int cls = bi >> 3, head = bi & 7;
    int ed = (cls >> 2) & 1, eh = (cls >> 1) & 1, ew = cls & 1;
    int j = tid & 127;
    int tdj = j >> 6, thj = (j >> 3) & 7, twj = j & 7;
    int regj = (ed ? (tdj + 1) : 0) * 9
             + (eh ? ((thj < 4) ? 1 : 2) : 0) * 3
             + (ew ? ((twj < 4) ? 1 : 2) : 0);
    ushort* bmp = bm + (long)bi * 16384;
    for (int ii = 0; ii < 64; ++ii) {
        int i = (tid >> 7) * 64 + ii;
        int tdi = i >> 6, thi = (i >> 3) & 7, twi = i & 7;
        int regi = (ed ? (tdi + 1) : 0) * 9
                 + (eh ? ((thi < 4) ? 1 : 2) : 0) * 3
                 + (ew ? ((twi < 4) ? 1 : 2) : 0);
        int rpi = (tdi - tdj + 1) * 225 + (thi - thj + 7) * 15 + (twi - twj + 7);
        float v = rpb[rpi * 8 + head] + ((regi != regj) ? -100.f : 0.f);
        bmp[i * 128 + j] = f2b(v);
    }
}

// ---------------------------------------------------------------------------
// K23 (unchanged from R7): one block per WINDOW, 512 threads = 8 waves.
// Phase A: LN1+shift+gather (4 thr/row). Phase B: QKV GEMM 4m x 2n.
// Phase C: 1 head per wave, R5-verified swapped-QK^T register softmax.
// O -> obuf [wi][head][tok][16].
// ---------------------------------------------------------------------------
__global__ __launch_bounds__(512) void k23(
    const float* __restrict__ x, const float* __restrict__ g,
    const float* __restrict__ be, const ushort* __restrict__ wq,
    const float* __restrict__ qkv_b, const ushort* __restrict__ bm,
    ushort* __restrict__ obuf)
{
    __shared__ __align__(16) ushort As[128][136];   // LN1 out; later V^T [h][16][136]
    __shared__ __align__(16) ushort qb[128][132];   // Q [tok][128ch]
    __shared__ __align__(16) ushort kb[128][132];   // K [tok][128ch]
    int tid = threadIdx.x;
    int wi = blockIdx.x;
    int wd = (wi >> 6) & 3, wh = (wi >> 3) & 7, ww = wi & 7;
    int cls = ((wd == 3) << 2) | ((wh == 7) << 1) | (ww == 7);
    {   // Phase A: LN + shift + gather -> As (4 threads per row)
        int row = tid >> 2, part = tid & 3;
        int b = wi >> 8;
        int td = row >> 6, th = (row >> 3) & 7, tw = row & 7;
        int d = (wd * 2 + td + 1) & 7;
        int h = (wh * 8 + th + 4) & 63;
        int w = (ww * 8 + tw + 4) & 63;
        long src = (((long)((b * 8 + d) * 64 + h)) * 64 + w) * 128 + part * 32;
        float vals[32];
        float s = 0.f, q = 0.f;
        #pragma unroll
        for (int i = 0; i < 8; ++i) {
            float4 u = *(const float4*)&x[src + i * 4];
            vals[i * 4 + 0] = u.x; vals[i * 4 + 1] = u.y;
            vals[i * 4 + 2] = u.z; vals[i * 4 + 3] = u.w;
            s += u.x + u.y + u.z + u.w;
            q += u.x * u.x + u.y * u.y + u.z * u.z + u.w * u.w;
        }
        s += __shfl_xor(s, 1); s += __shfl_xor(s, 2);
        q += __shfl_xor(q, 1); q += __shfl_xor(q, 2);
        float mean = s * (1.f / 128.f);
        float rstd = rsqrtf(q * (1.f / 128.f) - mean * mean + 1e-5f);
        #pragma unroll
        for (int i = 0; i < 4; ++i) {
            ushort pk[8];
            #pragma unroll
            for (int jj = 0; jj < 8; ++jj) {
                int c = part * 32 + i * 8 + jj;
                pk[jj] = f2b((vals[i * 8 + jj] - mean) * rstd * g[c] + be[c]);
            }
            *(uint4*)&As[row][part * 32 + i * 8] = *(uint4*)pk;
        }
    }
    __syncthreads();
    int wv = tid >> 6, lane = tid & 63, li = lane & 15, quad = lane >> 4;
    int wm = wv >> 1, wn = wv & 1;                  // wm 0..3, wn 0..1
    // Phase B: QKV GEMM -> LDS (q->qb, k->kb, v^T->As region)
    for (int nb = 0; nb < 3; ++nb) {
        f32x4 acc[2][4] = {};
        for (int s = 0; s < 4; ++s) {
            s16x8 a[2], bw[4];
            #pragma unroll
            for (int mi = 0; mi < 2; ++mi)
                a[mi] = *(const s16x8*)&As[wm * 32 + mi * 16 + li][s * 32 + quad * 8];
            #pragma unroll
            for (int ni = 0; ni < 4; ++ni)
                bw[ni] = *(const s16x8*)&wq[(long)(nb * 128 + wn * 64 + ni * 16 + li) * 128
                                            + s * 32 + quad * 8];
            #pragma unroll
            for (int mi = 0; mi < 2; ++mi)
                #pragma unroll
                for (int ni = 0; ni < 4; ++ni)
                    acc[mi][ni] = MFMA(a[mi], bw[ni], acc[mi][ni]);
        }
        if (nb == 2) __syncthreads();   // all As (A-operand) reads done before V^T overwrite
        #pragma unroll
        for (int mi = 0; mi < 2; ++mi)
            #pragma unroll
            for (int ni = 0; ni < 4; ++ni) {
                int gcol = nb * 128 + wn * 64 + ni * 16 + li;
                float bias = qkv_b[gcol];
                float scale = (nb == 0) ? 0.25f : 1.f;   // SCALE = 16^-0.5
                #pragma unroll
                for (int r = 0; r < 4; ++r) {
                    int trow = wm * 32 + mi * 16 + quad * 4 + r;
                    ushort val = f2b((acc[mi][ni][r] + bias) * scale);
                    if (nb == 0) {
                        qb[trow][gcol] = val;
                    } else if (nb == 1) {
                        kb[trow][gcol - 128] = val;
                    } else {
                        int c2 = gcol - 256, hh = c2 >> 4, dd = c2 & 15;
                        ((ushort*)As)[hh * 2176 + dd * 136 + trow] = val;  // V^T [h][d][tok]
                    }
                }
            }
    }
    __syncthreads();
    // Phase C: attention (R5-verified math), wave wv = head wv.
    const ushort* vtp = (const ushort*)As;
    {
        int h = wv;
        long bmb = (long)(cls * 8 + h) * 16384;
        long ob = (long)wi * 16384 + h * 2048;
        for (int qq = 0; qq < 4; ++qq) {
            int row0 = qq * 32;
            s16x4 qf0 = *(const s16x4*)&qb[row0 + li][h * 16 + quad * 4];
            s16x4 qf1 = *(const s16x4*)&qb[row0 + 16 + li][h * 16 + quad * 4];
            float ps0 = 0.f, ps1 = 0.f;
            uint pa0[8][2], pa1[8][2];
            #pragma unroll
            for (int mi = 0; mi < 8; ++mi) {
                s16x4 kf = *(const s16x4*)&kb[mi * 16 + li][h * 16 + quad * 4];
                f32x4 z = {0.f, 0.f, 0.f, 0.f};
                f32x4 s0 = MFMA16(kf, qf0, z);
                f32x4 s1 = MFMA16(kf, qf1, z);
                s16x4 b0 = *(const s16x4*)&bm[bmb + (row0 + li) * 128 + mi * 16 + quad * 4];
                s16x4 b1 = *(const s16x4*)&bm[bmb + (row0 + 16 + li) * 128 + mi * 16 + quad * 4];
                float e0 = __expf(s0[0] + b2f((ushort)b0[0]));
                float e1 = __expf(s0[1] + b2f((ushort)b0[1]));
                float e2 = __expf(s0[2] + b2f((ushort)b0[2]));
                float e3 = __expf(s0[3] + b2f((ushort)b0[3]));
                ps0 += (e0 + e1) + (e2 + e3);
                pa0[mi][0] = (uint)f2b(e0) | ((uint)f2b(e1) << 16);
                pa0[mi][1] = (uint)f2b(e2) | ((uint)f2b(e3) << 16);
                float f0 = __expf(s1[0] + b2f((ushort)b1[0]));
                float f1 = __expf(s1[1] + b2f((ushort)b1[1]));
                float f2 = __expf(s1[2] + b2f((ushort)b1[2]));
                float f3 = __expf(s1[3] + b2f((ushort)b1[3]));
                ps1 += (f0 + f1) + (f2 + f3);
                pa1[mi][0] = (uint)f2b(f0) | ((uint)f2b(f1) << 16);
                pa1[mi][1] = (uint)f2b(f2) | ((uint)f2b(f3) << 16);
            }
            ps0 += __shfl_xor(ps0, 16); ps0 += __shfl_xor(ps0, 32);
            ps1 += __shfl_xor(ps1, 16); ps1 += __shfl_xor(ps1, 32);
            float inv0 = 1.f / ps0, inv1 = 1.f / ps1;
            f32x4 pc0 = {0.f, 0.f, 0.f, 0.f}, pc1 = {0.f, 0.f, 0.f, 0.f};
            #pragma unroll
            for (int mi = 0; mi < 8; ++mi) {
                s16x4 vf = *(const s16x4*)&vtp[h * 2176 + li * 136 + mi * 16 + quad * 4];
                union { uint2 u; s16x4 v; } a0, a1;
                a0.u.x = pa0[mi][0]; a0.u.y = pa0[mi][1];
                a1.u.x = pa1[mi][0]; a1.u.y = pa1[mi][1];
                pc0 = MFMA16(a0.v, vf, pc0);
                pc1 = MFMA16(a1.v, vf, pc1);
            }
            #pragma unroll
            for (int r = 0; r < 4; ++r) {
                float oi0 = __shfl(inv0, quad * 4 + r);
                float oi1 = __shfl(inv1, quad * 4 + r);
                int i0 = row0 + quad * 4 + r;
                int i1 = row0 + 16 + quad * 4 + r;
                obuf[ob + (long)i0 * 16 + li] = f2b(pc0[r] * oi0);
                obuf[ob + (long)i1 * 16 + li] = f2b(pc1[r] * oi1);
            }
        }
    }
}

// ---------------------------------------------------------------------------
// K45 (R9): 64-token tile (proven optimum), 1024 x 256. x1 in 16 packed
// bf16x2 VGPRs (R2-proven, 112 VGPR no spill); hs DOUBLE-BUFFERED so the
// MLP hc-loop has ONE barrier per hc instead of two (12 -> 7 barriers
// total) and FC2(hc) overlaps FC1(hc+1). WAR on hs[hc&1] at hc+2 is
// protected by barrier(hc+1). LDS 51.7KB -> 3 blocks/CU static.
// ---------------------------------------------------------------------------
__global__ __launch_bounds__(256) void k45(
    const ushort* __restrict__ ao, const ushort* __restrict__ wp,
    const float* __restrict__ proj_b, const float* __restrict__ x,
    const float* __restrict__ g2, const float* __restrict__ be2,
    const ushort* __restrict__ wf1, const float* __restrict__ fc1_b,
    const ushort* __restrict__ wf2, const float* __restrict__ fc2_b,
    float* __restrict__ out)
{
    __shared__ __align__(16) ushort As[64][132];       // ao tile, later xs (LN2 out)
    __shared__ __align__(16) ushort hs[2][64][132];    // gelu(h) chunks, double-buffered
    __shared__ float redS[2][64];
    __shared__ float redQ[2][64];
    int tid = threadIdx.x;
    int b = blockIdx.x;
    int wi = b >> 1, half64 = b & 1;
    int wd = (wi >> 6) & 3, wh = (wi >> 3) & 7, ww = wi & 7;
    int bb = wi >> 8;
    long aob = (long)wi * 16384;
    int tok0 = half64 * 64;
    #pragma unroll
    for (int i = 0; i < 4; ++i) {
        int slot = tid + i * 256;               // 0..1023
        int row = slot & 63, hsl = slot >> 6;   // hsl = head*2 + (d-half)
        *(uint4*)&As[row][hsl * 8] =
            *(const uint4*)&ao[aob + (hsl >> 1) * 2048 + (long)(tok0 + row) * 16 + (hsl & 1) * 8];
    }
    __syncthreads();
    int wv = tid >> 6, lane = tid & 63, li = lane & 15, quad = lane >> 4;
    int wm = wv >> 1, wn = wv & 1;
    f32x4 acc[2][4] = {};
    for (int s = 0; s < 4; ++s) {
        s16x8 a[2], bw[4];
        #pragma unroll
        for (int mi = 0; mi < 2; ++mi)
            a[mi] = *(const s16x8*)&As[wm * 32 + mi * 16 + li][s * 32 + quad * 8];
        #pragma unroll
        for (int ni = 0; ni < 4; ++ni)
            bw[ni] = *(const s16x8*)&wp[(long)(wn * 64 + ni * 16 + li) * 128 + s * 32 + quad * 8];
        #pragma unroll
        for (int mi = 0; mi < 2; ++mi)
            #pragma unroll
            for (int ni = 0; ni < 4; ++ni)
                acc[mi][ni] = MFMA(a[mi], bw[ni], acc[mi][ni]);
    }
    // epilogue: x1 = acc + proj_b + x (f32, in-place in acc); LN2 row partials
    int cols[4];
    #pragma unroll
    for (int ni = 0; ni < 4; ++ni) cols[ni] = wn * 64 + ni * 16 + li;
    {
        float pbv[4];
        #pragma unroll
        for (int ni = 0; ni < 4; ++ni) pbv[ni] = proj_b[cols[ni]];
        #pragma unroll
        for (int mi = 0; mi < 2; ++mi) {
            #pragma unroll
            for (int r = 0; r < 4; ++r) {
                int lrow = wm * 32 + mi * 16 + quad * 4 + r;
                int t = half64 * 64 + lrow;
                int td = t >> 6, th = (t >> 3) & 7, tw = t & 7;
                int d = (wd * 2 + td + 1) & 7, h = (wh * 8 + th + 4) & 63, w = (ww * 8 + tw + 4) & 63;
                long di = (((long)((bb * 8 + d) * 64 + h)) * 64 + w) * 128;
                float s_ = 0.f, q_ = 0.f;
                #pragma unroll
                for (int ni = 0; ni < 4; ++ni) {
                    float v = acc[mi][ni][r] + pbv[ni] + x[di + cols[ni]];
                    acc[mi][ni][r] = v;
                    s_ += v; q_ += v * v;
                }
                #pragma unroll
                for (int m = 1; m < 16; m <<= 1) {
                    s_ += __shfl_xor(s_, m);
                    q_ += __shfl_xor(q_, m);
                }
                if (li == 0) { redS[wn][lrow] = s_; redQ[wn][lrow] = q_; }
            }
        }
    }
    __syncthreads();
    // LN2 normalize -> As (xs); pack x1 -> bf16x2 regs
    {
        float g2v[4], be2v[4];
        #pragma unroll
        for (int ni = 0; ni < 4; ++ni) { g2v[ni] = g2[cols[ni]]; be2v[ni] = be2[cols[ni]]; }
        #pragma unroll
        for (int mi = 0; mi < 2; ++mi) {
            #pragma unroll
            for (int r = 0; r < 4; ++r) {
                int lrow = wm * 32 + mi * 16 + quad * 4 + r;
                float tS = redS[0][lrow] + redS[1][lrow];
                float tQ = redQ[0][lrow] + redQ[1][lrow];
                float mean = tS * (1.f / 128.f);
                float rstd = rsqrtf(tQ * (1.f / 128.f) - mean * mean + 1e-5f);
                #pragma unroll
                for (int ni = 0; ni < 4; ++ni)
                    As[lrow][cols[ni]] = f2b((acc[mi][ni][r] - mean) * rstd * g2v[ni] + be2v[ni]);
            }
        }
    }
    uint x1p[2][4][2];
    #pragma unroll
    for (int mi = 0; mi < 2; ++mi)
        #pragma unroll
        for (int ni = 0; ni < 4; ++ni)
            #pragma unroll
            for (int rr = 0; rr < 2; ++rr)
                x1p[mi][ni][rr] = (unsigned int)f2b(acc[mi][ni][2 * rr])
                                | ((unsigned int)f2b(acc[mi][ni][2 * rr + 1]) << 16);
    __syncthreads();
    f32x4 yacc[2][4] = {};
    for (int hc = 0; hc < 4; ++hc) {
        f32x4 hacc[2][4] = {};
        #pragma unroll
        for (int kk = 0; kk < 4; ++kk) {
            s16x8 a[2], bw[4];
            #pragma unroll
            for (int mi = 0; mi < 2; ++mi)
                a[mi] = *(const s16x8*)&As[wm * 32 + mi * 16 + li][kk * 32 + quad * 8];
            #pragma unroll
            for (int ni = 0; ni < 4; ++ni)
                bw[ni] = *(const s16x8*)&wf1[(long)(hc * 128 + wn * 64 + ni * 16 + li) * 128
                                             + kk * 32 + quad * 8];
            #pragma unroll
            for (int mi = 0; mi < 2; ++mi)
                #pragma unroll
                for (int ni = 0; ni < 4; ++ni)
                    hacc[mi][ni] = MFMA(a[mi], bw[ni], hacc[mi][ni]);
        }
        #pragma unroll
        for (int mi = 0; mi < 2; ++mi)
            #pragma unroll
            for (int ni = 0; ni < 4; ++ni) {
                int col = wn * 64 + ni * 16 + li;
                float bbv = fc1_b[hc * 128 + col];
                #pragma unroll
                for (int r = 0; r < 4; ++r) {
                    int row = wm * 32 + mi * 16 + quad * 4 + r;
                    hs[hc & 1][row][col] = f2b(gelu_tanh(hacc[mi][ni][r] + bbv));
                }
            }
        __syncthreads();
        #pragma unroll
        for (int kk = 0; kk < 4; ++kk) {
            s16x8 a[2], bw[4];
            #pragma unroll
            for (int mi = 0; mi < 2; ++mi)
                a[mi] = *(const s16x8*)&hs[hc & 1][wm * 32 + mi * 16 + li][kk * 32 + quad * 8];
            #pragma unroll
            for (int ni = 0; ni < 4; ++ni)
                bw[ni] = *(const s16x8*)&wf2[(long)(wn * 64 + ni * 16 + li) * 512
                                             + hc * 128 + kk * 32 + quad * 8];
            #pragma unroll
            for (int mi = 0; mi < 2; ++mi)
                #pragma unroll
                for (int ni = 0; ni < 4; ++ni)
                    yacc[mi][ni] = MFMA(a[mi], bw[ni], yacc[mi][ni]);
        }
        // no trailing barrier: WAR on hs[hc&1] at hc+2 is fenced by barrier(hc+1)
    }
    {
        float f2v[4];
        #pragma unroll
        for (int ni = 0; ni < 4; ++ni) f2v[ni] = fc2_b[cols[ni]];
        #pragma unroll
        for (int mi = 0; mi < 2; ++mi) {
            #pragma unroll
            for (int r = 0; r < 4; ++r) {
                int lrow = wm * 32 + mi * 16 + quad * 4 + r;
                int t = half64 * 64 + lrow;
                int td = t >> 6, th = (t >> 3) & 7, tw = t & 7;
                int d = (wd * 2 + td + 1) & 7, h = (wh * 8 + th + 4) & 63, w = (ww * 8 + tw + 4) & 63;
                long di = (((long)((bb * 8 + d) * 64 + h)) * 64 + w) * 128;
                #pragma unroll
                for (int ni = 0; ni < 4; ++ni) {
                    unsigned int wrd = x1p[mi][ni][r >> 1];
                    float x1v = b2f((ushort)((wrd >> ((r & 1) * 16)) & 0xffffu));
                    out[di + cols[ni]] = x1v + yacc[mi][ni][r] + f2v[ni];
                }
            }
        }
    }
}

// ---------------------------------------------------------------------------
// ws layout:
//   [0 .. 16.8MB): obuf = attn-out, [wi][head][tok][16] (window stride 16384).
//   tail (fixed offsets, unchanged): wq 96KB | wp 32KB | wf 256KB | bm 2MB.
// d_out holds ONLY the final f32 output (no scratch -> no races).
// ---------------------------------------------------------------------------
extern "C" void kernel_launch(void* const* d_in, const int* in_sizes, int n_in,
                              void* d_out, int out_size, void* d_ws, size_t ws_size,
                              hipStream_t stream)
{
    (void)in_sizes; (void)n_in; (void)out_size; (void)ws_size;
    const float* x      = (const float*)d_in[0];
    const float* qkv_w  = (const float*)d_in[1];
    const float* qkv_b  = (const float*)d_in[2];
    const float* proj_w = (const float*)d_in[3];
    const float* proj_b = (const float*)d_in[4];
    const float* rpb    = (const float*)d_in[5];
    const float* ln1_g  = (const float*)d_in[6];
    const float* ln1_b  = (const float*)d_in[7];
    const float* ln2_g  = (const float*)d_in[8];
    const float* ln2_b  = (const float*)d_in[9];
    const float* fc1_w  = (const float*)d_in[10];
    const float* fc1_b  = (const float*)d_in[11];
    const float* fc2_w  = (const float*)d_in[12];
    const float* fc2_b  = (const float*)d_in[13];
    float* out = (float*)d_out;

    ushort* obuf = (ushort*)d_ws;                       // 16.8 MB used
    ushort* wq   = (ushort*)((char*)d_ws + 50331648);   // 49152 elems
    ushort* wp   = wq + 49152;                          // 16384
    ushort* wf   = wp + 16384;                          // 131072
    ushort* bm   = wf + 131072;                         // 1048576

    hipLaunchKernelGGL(k0_prep, dim3(832), dim3(256), 0, stream,
                       qkv_w, proj_w, fc1_w, fc2_w, rpb, wq, wp, wf, bm);
    hipLaunchKernelGGL(k23, dim3(512), dim3(512), 0, stream,
                       x, ln1_g, ln1_b, wq, qkv_b, bm, obuf);
    hipLaunchKernelGGL(k45, dim3(1024), dim3(256), 0, stream,
                       obuf, wp, proj_b, x, ln2_g, ln2_b,
                       wf, fc1_b, wf + 65536, fc2_b, out);
}

// Round 10
// 267.474 us; speedup vs baseline: 1.2024x; 1.0265x over previous
//
#include <hip/hip_runtime.h>
#include <math.h>

typedef short s16x8 __attribute__((ext_vector_type(8)));
typedef short s16x4 __attribute__((ext_vector_type(4)));
typedef float f32x4 __attribute__((ext_vector_type(4)));

#define MFMA(a, b, c)    __builtin_amdgcn_mfma_f32_16x16x32_bf16(a, b, c, 0, 0, 0)
#define MFMA16(a, b, c)  __builtin_amdgcn_mfma_f32_16x16x16bf16_1k(a, b, c, 0, 0, 0)

__device__ __forceinline__ float b2f(ushort u) {
    union { unsigned int i; float f; } v; v.i = ((unsigned int)u) << 16; return v.f;
}
__device__ __forceinline__ ushort f2b(float f) {
    union { float f; unsigned int i; } v; v.f = f;
    unsigned int r = v.i + 0x7fffu + ((v.i >> 16) & 1u);
    return (ushort)(r >> 16);
}
__device__ __forceinline__ float gelu_tanh(float v) {
    float u = 0.7978845608f * (v + 0.044715f * v * v * v);
    float e = __expf(-2.f * fabsf(u));
    float t = (1.f - e) / (1.f + e);            // tanh(|u|)
    t = (u < 0.f) ? -t : t;
    return 0.5f * v * (1.f + t);
}

// ---------------------------------------------------------------------------
// K0: all prep. blocks [0,192): qkv_w->wq; [192,256): proj_w->wp;
// [256,768): fc1/fc2->wf; [768,832): bias+mask table bm[cls][head][128][128].
// ---------------------------------------------------------------------------
__global__ __launch_bounds__(256) void k0_prep(
    const float* __restrict__ qkv_w, const float* __restrict__ proj_w,
    const float* __restrict__ fc1_w, const float* __restrict__ fc2_w,
    const float* __restrict__ rpb, ushort* __restrict__ wq,
    ushort* __restrict__ wp, ushort* __restrict__ wf, ushort* __restrict__ bm)
{
    int bid = blockIdx.x, tid = threadIdx.x;
    if (bid < 192) { int idx = bid * 256 + tid; wq[idx] = f2b(qkv_w[idx]); return; }
    if (bid < 256) { int idx = (bid - 192) * 256 + tid; wp[idx] = f2b(proj_w[idx]); return; }
    if (bid < 768) {
        int idx = (bid - 256) * 256 + tid;
        wf[idx] = f2b(idx < 65536 ? fc1_w[idx] : fc2_w[idx - 65536]);
        return;
    }
    int bi = bid - 768;                             // [0,64) = cls*8+head
    int cls = bi >> 3, head = bi & 7;
    int ed = (cls >> 2) & 1, eh = (cls >> 1) & 1, ew = cls & 1;
    int j = tid & 127;
    int tdj = j >> 6, thj = (j >> 3) & 7, twj = j & 7;
    int regj = (ed ? (tdj + 1) : 0) * 9
             + (eh ? ((thj < 4) ? 1 : 2) : 0) * 3
             + (ew ? ((twj < 4) ? 1 : 2) : 0);
    ushort* bmp = bm + (long)bi * 16384;
    for (int ii = 0; ii < 64; ++ii) {
        int i = (tid >> 7) * 64 + ii;
        int tdi = i >> 6, thi = (i >> 3) & 7, twi = i & 7;
        int regi = (ed ? (tdi + 1) : 0) * 9
                 + (eh ? ((thi < 4) ? 1 : 2) : 0) * 3
                 + (ew ? ((twi < 4) ? 1 : 2) : 0);
        int rpi = (tdi - tdj + 1) * 225 + (thi - thj + 7) * 15 + (twi - twj + 7);
        float v = rpb[rpi * 8 + head] + ((regi != regj) ? -100.f : 0.f);
        bmp[i * 128 + j] = f2b(v);
    }
}

// ---------------------------------------------------------------------------
// K23 (R10: head-half split). grid 1024 = 512 windows x 2 halves, 256 thr
// (4 waves). Each block: phase A = full LN1+gather (redundant per half; x
// read 2x, L3-resident); phase B = QKV GEMM for ITS 4 heads only (192 of
// 384 cols, acc[4][2]); phase C = 1 head/wave (R7-verified math). LDS
// 68KB -> 2 blocks/CU: phases now overlap ACROSS blocks (k23 previously
// ran 1 block/CU with zero cross-block latency hiding).
// ---------------------------------------------------------------------------
__global__ __launch_bounds__(256) void k23(
    const float* __restrict__ x, const float* __restrict__ g,
    const float* __restrict__ be, const ushort* __restrict__ wq,
    const float* __restrict__ qkv_b, const ushort* __restrict__ bm,
    ushort* __restrict__ obuf)
{
    __shared__ __align__(16) ushort As[128][136];   // LN1 out; later V^T [4hl][16][136]
    __shared__ __align__(16) ushort qb[128][68];    // Q [tok][64ch local]
    __shared__ __align__(16) ushort kb[128][68];    // K [tok][64ch local]
    int tid = threadIdx.x;
    int wi = blockIdx.x >> 1, hh = blockIdx.x & 1;
    int wd = (wi >> 6) & 3, wh = (wi >> 3) & 7, ww = wi & 7;
    int cls = ((wd == 3) << 2) | ((wh == 7) << 1) | (ww == 7);
    {   // Phase A: LN + shift + gather -> As (2 threads per row)
        int row = tid >> 1, half = tid & 1;
        int b = wi >> 8;
        int td = row >> 6, th = (row >> 3) & 7, tw = row & 7;
        int d = (wd * 2 + td + 1) & 7;
        int h = (wh * 8 + th + 4) & 63;
        int w = (ww * 8 + tw + 4) & 63;
        long src = (((long)((b * 8 + d) * 64 + h)) * 64 + w) * 128 + half * 64;
        float vals[64];
        float s = 0.f, q = 0.f;
        #pragma unroll
        for (int i = 0; i < 16; ++i) {
            float4 u = *(const float4*)&x[src + i * 4];
            vals[i * 4 + 0] = u.x; vals[i * 4 + 1] = u.y;
            vals[i * 4 + 2] = u.z; vals[i * 4 + 3] = u.w;
            s += u.x + u.y + u.z + u.w;
            q += u.x * u.x + u.y * u.y + u.z * u.z + u.w * u.w;
        }
        s += __shfl_xor(s, 1);
        q += __shfl_xor(q, 1);
        float mean = s * (1.f / 128.f);
        float rstd = rsqrtf(q * (1.f / 128.f) - mean * mean + 1e-5f);
        #pragma unroll
        for (int i = 0; i < 8; ++i) {
            ushort pk[8];
            #pragma unroll
            for (int jj = 0; jj < 8; ++jj) {
                int c = half * 64 + i * 8 + jj;
                pk[jj] = f2b((vals[i * 8 + jj] - mean) * rstd * g[c] + be[c]);
            }
            *(uint4*)&As[row][half * 64 + i * 8] = *(uint4*)pk;
        }
    }
    __syncthreads();
    int wv = tid >> 6, lane = tid & 63, li = lane & 15, quad = lane >> 4;
    int wm = wv >> 1, wn = wv & 1;                  // wm 0..1 (64 rows), wn 0..1 (32 cols)
    // Phase B: QKV GEMM for this half's 4 heads (64 cols per mat)
    for (int nb = 0; nb < 3; ++nb) {
        f32x4 acc[4][2] = {};
        for (int s = 0; s < 4; ++s) {
            s16x8 a[4], bw[2];
            #pragma unroll
            for (int mi = 0; mi < 4; ++mi)
                a[mi] = *(const s16x8*)&As[wm * 64 + mi * 16 + li][s * 32 + quad * 8];
            #pragma unroll
            for (int ni = 0; ni < 2; ++ni)
                bw[ni] = *(const s16x8*)&wq[(long)(nb * 128 + hh * 64 + wn * 32 + ni * 16 + li) * 128
                                            + s * 32 + quad * 8];
            #pragma unroll
            for (int mi = 0; mi < 4; ++mi)
                #pragma unroll
                for (int ni = 0; ni < 2; ++ni)
                    acc[mi][ni] = MFMA(a[mi], bw[ni], acc[mi][ni]);
        }
        if (nb == 2) __syncthreads();   // all As (A-operand) reads done before V^T overwrite
        #pragma unroll
        for (int mi = 0; mi < 4; ++mi)
            #pragma unroll
            for (int ni = 0; ni < 2; ++ni) {
                int lcol = wn * 32 + ni * 16 + li;          // 0..63
                int gcol = nb * 128 + hh * 64 + lcol;
                float bias = qkv_b[gcol];
                float scale = (nb == 0) ? 0.25f : 1.f;      // SCALE = 16^-0.5
                #pragma unroll
                for (int r = 0; r < 4; ++r) {
                    int trow = wm * 64 + mi * 16 + quad * 4 + r;
                    ushort val = f2b((acc[mi][ni][r] + bias) * scale);
                    if (nb == 0) {
                        qb[trow][lcol] = val;
                    } else if (nb == 1) {
                        kb[trow][lcol] = val;
                    } else {
                        int hl = lcol >> 4, dd = lcol & 15;
                        ((ushort*)As)[hl * 2176 + dd * 136 + trow] = val;  // V^T [hl][d][tok]
                    }
                }
            }
    }
    __syncthreads();
    // Phase C: attention (R5/R7-verified math), wave wv -> local head wv.
    const ushort* vtp = (const ushort*)As;
    {
        int hl = wv, hg = hh * 4 + wv;
        long bmb = (long)(cls * 8 + hg) * 16384;
        long ob = (long)wi * 16384 + hg * 2048;
        for (int qq = 0; qq < 4; ++qq) {
            int row0 = qq * 32;
            s16x4 qf0 = *(const s16x4*)&qb[row0 + li][hl * 16 + quad * 4];
            s16x4 qf1 = *(const s16x4*)&qb[row0 + 16 + li][hl * 16 + quad * 4];
            float ps0 = 0.f, ps1 = 0.f;
            uint pa0[8][2], pa1[8][2];
            #pragma unroll
            for (int mi = 0; mi < 8; ++mi) {
                s16x4 kf = *(const s16x4*)&kb[mi * 16 + li][hl * 16 + quad * 4];
                f32x4 z = {0.f, 0.f, 0.f, 0.f};
                f32x4 s0 = MFMA16(kf, qf0, z);
                f32x4 s1 = MFMA16(kf, qf1, z);
                s16x4 b0 = *(const s16x4*)&bm[bmb + (row0 + li) * 128 + mi * 16 + quad * 4];
                s16x4 b1 = *(const s16x4*)&bm[bmb + (row0 + 16 + li) * 128 + mi * 16 + quad * 4];
                float e0 = __expf(s0[0] + b2f((ushort)b0[0]));
                float e1 = __expf(s0[1] + b2f((ushort)b0[1]));
                float e2 = __expf(s0[2] + b2f((ushort)b0[2]));
                float e3 = __expf(s0[3] + b2f((ushort)b0[3]));
                ps0 += (e0 + e1) + (e2 + e3);
                pa0[mi][0] = (uint)f2b(e0) | ((uint)f2b(e1) << 16);
                pa0[mi][1] = (uint)f2b(e2) | ((uint)f2b(e3) << 16);
                float f0 = __expf(s1[0] + b2f((ushort)b1[0]));
                float f1 = __expf(s1[1] + b2f((ushort)b1[1]));
                float f2 = __expf(s1[2] + b2f((ushort)b1[2]));
                float f3 = __expf(s1[3] + b2f((ushort)b1[3]));
                ps1 += (f0 + f1) + (f2 + f3);
                pa1[mi][0] = (uint)f2b(f0) | ((uint)f2b(f1) << 16);
                pa1[mi][1] = (uint)f2b(f2) | ((uint)f2b(f3) << 16);
            }
            ps0 += __shfl_xor(ps0, 16); ps0 += __shfl_xor(ps0, 32);
            ps1 += __shfl_xor(ps1, 16); ps1 += __shfl_xor(ps1, 32);
            float inv0 = 1.f / ps0, inv1 = 1.f / ps1;
            f32x4 pc0 = {0.f, 0.f, 0.f, 0.f}, pc1 = {0.f, 0.f, 0.f, 0.f};
            #pragma unroll
            for (int mi = 0; mi < 8; ++mi) {
                s16x4 vf = *(const s16x4*)&vtp[hl * 2176 + li * 136 + mi * 16 + quad * 4];
                union { uint2 u; s16x4 v; } a0, a1;
                a0.u.x = pa0[mi][0]; a0.u.y = pa0[mi][1];
                a1.u.x = pa1[mi][0]; a1.u.y = pa1[mi][1];
                pc0 = MFMA16(a0.v, vf, pc0);
                pc1 = MFMA16(a1.v, vf, pc1);
            }
            #pragma unroll
            for (int r = 0; r < 4; ++r) {
                float oi0 = __shfl(inv0, quad * 4 + r);
                float oi1 = __shfl(inv1, quad * 4 + r);
                int i0 = row0 + quad * 4 + r;
                int i1 = row0 + 16 + quad * 4 + r;
                obuf[ob + (long)i0 * 16 + li] = f2b(pc0[r] * oi0);
                obuf[ob + (long)i1 * 16 + li] = f2b(pc1[r] * oi1);
            }
        }
    }
}

// ---------------------------------------------------------------------------
// K45 (R10): reverted to the proven R0/R5 shape (103.3-104.1us measured
// across R5/R6/R7): 64-token tile, 1024x256, x1 in x1t LDS (VGPR 96, no
// spill), 12 barriers, LDS 52.7KB. ao = compact O buffer [wi][head][tok][16].
// ---------------------------------------------------------------------------
__global__ __launch_bounds__(256) void k45(
    const ushort* __restrict__ ao, const ushort* __restrict__ wp,
    const float* __restrict__ proj_b, const float* __restrict__ x,
    const float* __restrict__ g2, const float* __restrict__ be2,
    const ushort* __restrict__ wf1, const float* __restrict__ fc1_b,
    const ushort* __restrict__ wf2, const float* __restrict__ fc2_b,
    float* __restrict__ out)
{
    __shared__ __align__(16) ushort As[64][132];    // ao tile, later xs (LN2 out)
    __shared__ __align__(16) ushort x1t[64][132];   // x1 (bf16)
    __shared__ __align__(16) ushort hs[64][132];    // gelu(h) chunk
    __shared__ float redS[4][64];
    __shared__ float redQ[4][64];
    int tid = threadIdx.x;
    int b = blockIdx.x;
    int wi = b >> 1, half64 = b & 1;
    int wd = (wi >> 6) & 3, wh = (wi >> 3) & 7, ww = wi & 7;
    int bb = wi >> 8;
    long aob = (long)wi * 16384;
    int tok0 = half64 * 64;
    #pragma unroll
    for (int i = 0; i < 4; ++i) {
        int slot = tid + i * 256;               // 0..1023
        int row = slot & 63, hsl = slot >> 6;   // hsl = head*2 + (d-half)
        *(uint4*)&As[row][hsl * 8] =
            *(const uint4*)&ao[aob + (hsl >> 1) * 2048 + (long)(tok0 + row) * 16 + (hsl & 1) * 8];
    }
    __syncthreads();
    int wv = tid >> 6, lane = tid & 63, li = lane & 15, quad = lane >> 4;
    int wm = wv >> 1, wn = wv & 1;
    f32x4 acc[2][4] = {};
    for (int s = 0; s < 4; ++s) {
        s16x8 a[2], bw[4];
        #pragma unroll
        for (int mi = 0; mi < 2; ++mi)
            a[mi] = *(const s16x8*)&As[wm * 32 + mi * 16 + li][s * 32 + quad * 8];
        #pragma unroll
        for (int ni = 0; ni < 4; ++ni)
            bw[ni] = *(const s16x8*)&wp[(long)(wn * 64 + ni * 16 + li) * 128 + s * 32 + quad * 8];
        #pragma unroll
        for (int mi = 0; mi < 2; ++mi)
            #pragma unroll
            for (int ni = 0; ni < 4; ++ni)
                acc[mi][ni] = MFMA(a[mi], bw[ni], acc[mi][ni]);
    }
    // epilogue: residual add (f32 x) -> x1t (bf16)
    #pragma unroll
    for (int mi = 0; mi < 2; ++mi) {
        #pragma unroll
        for (int r = 0; r < 4; ++r) {
            int lrow = wm * 32 + mi * 16 + quad * 4 + r;
            int t = half64 * 64 + lrow;
            int td = t >> 6, th = (t >> 3) & 7, tw = t & 7;
            int d = (wd * 2 + td + 1) & 7, h = (wh * 8 + th + 4) & 63, w = (ww * 8 + tw + 4) & 63;
            long di = (((long)((bb * 8 + d) * 64 + h)) * 64 + w) * 128;
            #pragma unroll
            for (int ni = 0; ni < 4; ++ni) {
                int col = wn * 64 + ni * 16 + li;
                x1t[lrow][col] = f2b(acc[mi][ni][r] + proj_b[col] + x[di + col]);
            }
        }
    }
    __syncthreads();
    {   // LN2 from x1t -> xs (reuse As)
        int token = tid & 63, part = tid >> 6;
        float vals[32];
        float s = 0.f, q = 0.f;
        #pragma unroll
        for (int i = 0; i < 4; ++i) {
            uint4 u = *(const uint4*)&x1t[token][part * 32 + i * 8];
            const ushort* p = (const ushort*)&u;
            #pragma unroll
            for (int j = 0; j < 8; ++j) { float f = b2f(p[j]); vals[i * 8 + j] = f; s += f; q += f * f; }
        }
        redS[part][token] = s; redQ[part][token] = q;
        __syncthreads();
        float st = 0.f, qt = 0.f;
        #pragma unroll
        for (int p2 = 0; p2 < 4; ++p2) { st += redS[p2][token]; qt += redQ[p2][token]; }
        float mean = st * (1.f / 128.f);
        float rstd = rsqrtf(qt * (1.f / 128.f) - mean * mean + 1e-5f);
        #pragma unroll
        for (int i = 0; i < 4; ++i) {
            ushort packed[8];
            #pragma unroll
            for (int j = 0; j < 8; ++j) {
                int c = part * 32 + i * 8 + j;
                packed[j] = f2b((vals[i * 8 + j] - mean) * rstd * g2[c] + be2[c]);
            }
            *(uint4*)&As[token][part * 32 + i * 8] = *(uint4*)packed;
        }
    }
    __syncthreads();
    f32x4 yacc[2][4] = {};
    for (int hc = 0; hc < 4; ++hc) {
        f32x4 hacc[2][4] = {};
        #pragma unroll
        for (int kk = 0; kk < 4; ++kk) {
            s16x8 a[2], bw[4];
            #pragma unroll
            for (int mi = 0; mi < 2; ++mi)
                a[mi] = *(const s16x8*)&As[wm * 32 + mi * 16 + li][kk * 32 + quad * 8];
            #pragma unroll
            for (int ni = 0; ni < 4; ++ni)
                bw[ni] = *(const s16x8*)&wf1[(long)(hc * 128 + wn * 64 + ni * 16 + li) * 128
                                             + kk * 32 + quad * 8];
            #pragma unroll
            for (int mi = 0; mi < 2; ++mi)
                #pragma unroll
                for (int ni = 0; ni < 4; ++ni)
                    hacc[mi][ni] = MFMA(a[mi], bw[ni], hacc[mi][ni]);
        }
        #pragma unroll
        for (int mi = 0; mi < 2; ++mi)
            #pragma unroll
            for (int ni = 0; ni < 4; ++ni) {
                int col = wn * 64 + ni * 16 + li;
                float bbv = fc1_b[hc * 128 + col];
                #pragma unroll
                for (int r = 0; r < 4; ++r) {
                    int row = wm * 32 + mi * 16 + quad * 4 + r;
                    hs[row][col] = f2b(gelu_tanh(hacc[mi][ni][r] + bbv));
                }
            }
        __syncthreads();
        #pragma unroll
        for (int kk = 0; kk < 4; ++kk) {
            s16x8 a[2], bw[4];
            #pragma unroll
            for (int mi = 0; mi < 2; ++mi)
                a[mi] = *(const s16x8*)&hs[wm * 32 + mi * 16 + li][kk * 32 + quad * 8];
            #pragma unroll
            for (int ni = 0; ni < 4; ++ni)
                bw[ni] = *(const s16x8*)&wf2[(long)(wn * 64 + ni * 16 + li) * 512
                                             + hc * 128 + kk * 32 + quad * 8];
            #pragma unroll
            for (int mi = 0; mi < 2; ++mi)
                #pragma unroll
                for (int ni = 0; ni < 4; ++ni)
                    yacc[mi][ni] = MFMA(a[mi], bw[ni], yacc[mi][ni]);
        }
        __syncthreads();
    }
    #pragma unroll
    for (int mi = 0; mi < 2; ++mi) {
        #pragma unroll
        for (int r = 0; r < 4; ++r) {
            int lrow = wm * 32 + mi * 16 + quad * 4 + r;
            int t = half64 * 64 + lrow;
            int td = t >> 6, th = (t >> 3) & 7, tw = t & 7;
            int d = (wd * 2 + td + 1) & 7, h = (wh * 8 + th + 4) & 63, w = (ww * 8 + tw + 4) & 63;
            long di = (((long)((bb * 8 + d) * 64 + h)) * 64 + w) * 128;
            #pragma unroll
            for (int ni = 0; ni < 4; ++ni) {
                int col = wn * 64 + ni * 16 + li;
                out[di + col] = b2f(x1t[lrow][col]) + yacc[mi][ni][r] + fc2_b[col];
            }
        }
    }
}

// ---------------------------------------------------------------------------
// ws layout (compacted, ~18.4MB):
//   [0 .. 16MB): obuf = attn-out, [wi][head][tok][16] (window stride 16384).
//   tail: wq 96KB | wp 32KB | wf 256KB | bm 2MB (directly after obuf).
// d_out holds ONLY the final f32 output (no scratch -> no races).
// ---------------------------------------------------------------------------
extern "C" void kernel_launch(void* const* d_in, const int* in_sizes, int n_in,
                              void* d_out, int out_size, void* d_ws, size_t ws_size,
                              hipStream_t stream)
{
    (void)in_sizes; (void)n_in; (void)out_size; (void)ws_size;
    const float* x      = (const float*)d_in[0];
    const float* qkv_w  = (const float*)d_in[1];
    const float* qkv_b  = (const float*)d_in[2];
    const float* proj_w = (const float*)d_in[3];
    const float* proj_b = (const float*)d_in[4];
    const float* rpb    = (const float*)d_in[5];
    const float* ln1_g  = (const float*)d_in[6];
    const float* ln1_b  = (const float*)d_in[7];
    const float* ln2_g  = (const float*)d_in[8];
    const float* ln2_b  = (const float*)d_in[9];
    const float* fc1_w  = (const float*)d_in[10];
    const float* fc1_b  = (const float*)d_in[11];
    const float* fc2_w  = (const float*)d_in[12];
    const float* fc2_b  = (const float*)d_in[13];
    float* out = (float*)d_out;

    ushort* obuf = (ushort*)d_ws;                       // 16 MB
    ushort* wq   = (ushort*)((char*)d_ws + 16777216);   // 49152 elems
    ushort* wp   = wq + 49152;                          // 16384
    ushort* wf   = wp + 16384;                          // 131072
    ushort* bm   = wf + 131072;                         // 1048576

    hipLaunchKernelGGL(k0_prep, dim3(832), dim3(256), 0, stream,
                       qkv_w, proj_w, fc1_w, fc2_w, rpb, wq, wp, wf, bm);
    hipLaunchKernelGGL(k23, dim3(1024), dim3(256), 0, stream,
                       x, ln1_g, ln1_b, wq, qkv_b, bm, obuf);
    hipLaunchKernelGGL(k45, dim3(1024), dim3(256), 0, stream,
                       obuf, wp, proj_b, x, ln2_g, ln2_b,
                       wf, fc1_b, wf + 65536, fc2_b, out);
}

// Round 11
// 260.868 us; speedup vs baseline: 1.2329x; 1.0253x over previous
//
#include <hip/hip_runtime.h>
#include <math.h>

typedef short s16x8 __attribute__((ext_vector_type(8)));
typedef short s16x4 __attribute__((ext_vector_type(4)));
typedef float f32x4 __attribute__((ext_vector_type(4)));

#define MFMA(a, b, c)    __builtin_amdgcn_mfma_f32_16x16x32_bf16(a, b, c, 0, 0, 0)
#define MFMA16(a, b, c)  __builtin_amdgcn_mfma_f32_16x16x16bf16_1k(a, b, c, 0, 0, 0)

__device__ __forceinline__ float b2f(ushort u) {
    union { unsigned int i; float f; } v; v.i = ((unsigned int)u) << 16; return v.f;
}
__device__ __forceinline__ ushort f2b(float f) {
    union { float f; unsigned int i; } v; v.f = f;
    unsigned int r = v.i + 0x7fffu + ((v.i >> 16) & 1u);
    return (ushort)(r >> 16);
}
__device__ __forceinline__ float gelu_tanh(float v) {
    float u = 0.7978845608f * (v + 0.044715f * v * v * v);
    float e = __expf(-2.f * fabsf(u));
    float t = (1.f - e) / (1.f + e);            // tanh(|u|)
    t = (u < 0.f) ? -t : t;
    return 0.5f * v * (1.f + t);
}

// ---------------------------------------------------------------------------
// K0 (R11 rewrite): much wider parallelism.
// blocks [0,192): ALL weight conversion, vectorized — unified dst index
//   u = bid*1024 + tid*4 over contiguous wq|wp|wf (196608 ushorts); float4
//   source load (boundaries 49152/65536/131072 are all x4 -> no straddle).
// blocks [192,704): bm table, 512 blocks (was 64): bi=(b-192)>>3 picks
//   (cls,head), seg=(b-192)&7 picks 16 rows; 8 iterations/thread (was 64).
// Identical output bytes to the old k0.
// ---------------------------------------------------------------------------
__global__ __launch_bounds__(256) void k0_prep(
    const float* __restrict__ qkv_w, const float* __restrict__ proj_w,
    const float* __restrict__ fc1_w, const float* __restrict__ fc2_w,
    const float* __restrict__ rpb, ushort* __restrict__ wq,
    ushort* __restrict__ wp, ushort* __restrict__ wf, ushort* __restrict__ bm)
{
    (void)wp; (void)wf;   // wq|wp|wf contiguous: addressed via wq + u
    int bid = blockIdx.x, tid = threadIdx.x;
    if (bid < 192) {
        int u = bid * 1024 + tid * 4;
        const float* src;
        if (u < 49152)       src = qkv_w + u;
        else if (u < 65536)  src = proj_w + (u - 49152);
        else if (u < 131072) src = fc1_w + (u - 65536);
        else                 src = fc2_w + (u - 131072);
        float4 v = *(const float4*)src;
        union { ushort us[4]; uint2 u2; } pk;
        pk.us[0] = f2b(v.x); pk.us[1] = f2b(v.y);
        pk.us[2] = f2b(v.z); pk.us[3] = f2b(v.w);
        *(uint2*)&wq[u] = pk.u2;
        return;
    }
    int bb = bid - 192;
    int bi = bb >> 3, seg = bb & 7;                 // bi = cls*8+head, seg = row/16
    int cls = bi >> 3, head = bi & 7;
    int ed = (cls >> 2) & 1, eh = (cls >> 1) & 1, ew = cls & 1;
    int j = tid & 127;
    int tdj = j >> 6, thj = (j >> 3) & 7, twj = j & 7;
    int regj = (ed ? (tdj + 1) : 0) * 9
             + (eh ? ((thj < 4) ? 1 : 2) : 0) * 3
             + (ew ? ((twj < 4) ? 1 : 2) : 0);
    ushort* bmp = bm + (long)bi * 16384;
    int i0 = seg * 16 + (tid >> 7) * 8;
    for (int ii = 0; ii < 8; ++ii) {
        int i = i0 + ii;
        int tdi = i >> 6, thi = (i >> 3) & 7, twi = i & 7;
        int regi = (ed ? (tdi + 1) : 0) * 9
                 + (eh ? ((thi < 4) ? 1 : 2) : 0) * 3
                 + (ew ? ((twi < 4) ? 1 : 2) : 0);
        int rpi = (tdi - tdj + 1) * 225 + (thi - thj + 7) * 15 + (twi - twj + 7);
        float v = rpb[rpi * 8 + head] + ((regi != regj) ? -100.f : 0.f);
        bmp[i * 128 + j] = f2b(v);
    }
}

// ---------------------------------------------------------------------------
// K23 (R11: same-XCD half-pairing). Structure identical to R10 (head-half
// split, 1024 x 256, LDS 68KB -> 2 blocks/CU). Only the bid->(wi,hh) map
// changed: wi = (bid>>4)*8 + (bid&7), hh = (bid>>3)&1, so the two halves
// of a window have equal bid%8 (same XCD under round-robin) and are
// dispatched 8 slots apart -> the 2nd half's phase-A x-reads hit L2.
// ---------------------------------------------------------------------------
__global__ __launch_bounds__(256) void k23(
    const float* __restrict__ x, const float* __restrict__ g,
    const float* __restrict__ be, const ushort* __restrict__ wq,
    const float* __restrict__ qkv_b, const ushort* __restrict__ bm,
    ushort* __restrict__ obuf)
{
    __shared__ __align__(16) ushort As[128][136];   // LN1 out; later V^T [4hl][16][136]
    __shared__ __align__(16) ushort qb[128][68];    // Q [tok][64ch local]
    __shared__ __align__(16) ushort kb[128][68];    // K [tok][64ch local]
    int tid = threadIdx.x;
    int bid = blockIdx.x;
    int wi = (bid >> 4) * 8 + (bid & 7);            // [0,512)
    int hh = (bid >> 3) & 1;
    int wd = (wi >> 6) & 3, wh = (wi >> 3) & 7, ww = wi & 7;
    int cls = ((wd == 3) << 2) | ((wh == 7) << 1) | (ww == 7);
    {   // Phase A: LN + shift + gather -> As (2 threads per row)
        int row = tid >> 1, half = tid & 1;
        int b = wi >> 8;
        int td = row >> 6, th = (row >> 3) & 7, tw = row & 7;
        int d = (wd * 2 + td + 1) & 7;
        int h = (wh * 8 + th + 4) & 63;
        int w = (ww * 8 + tw + 4) & 63;
        long src = (((long)((b * 8 + d) * 64 + h)) * 64 + w) * 128 + half * 64;
        float vals[64];
        float s = 0.f, q = 0.f;
        #pragma unroll
        for (int i = 0; i < 16; ++i) {
            float4 u = *(const float4*)&x[src + i * 4];
            vals[i * 4 + 0] = u.x; vals[i * 4 + 1] = u.y;
            vals[i * 4 + 2] = u.z; vals[i * 4 + 3] = u.w;
            s += u.x + u.y + u.z + u.w;
            q += u.x * u.x + u.y * u.y + u.z * u.z + u.w * u.w;
        }
        s += __shfl_xor(s, 1);
        q += __shfl_xor(q, 1);
        float mean = s * (1.f / 128.f);
        float rstd = rsqrtf(q * (1.f / 128.f) - mean * mean + 1e-5f);
        #pragma unroll
        for (int i = 0; i < 8; ++i) {
            ushort pk[8];
            #pragma unroll
            for (int jj = 0; jj < 8; ++jj) {
                int c = half * 64 + i * 8 + jj;
                pk[jj] = f2b((vals[i * 8 + jj] - mean) * rstd * g[c] + be[c]);
            }
            *(uint4*)&As[row][half * 64 + i * 8] = *(uint4*)pk;
        }
    }
    __syncthreads();
    int wv = tid >> 6, lane = tid & 63, li = lane & 15, quad = lane >> 4;
    int wm = wv >> 1, wn = wv & 1;                  // wm 0..1 (64 rows), wn 0..1 (32 cols)
    // Phase B: QKV GEMM for this half's 4 heads (64 cols per mat)
    for (int nb = 0; nb < 3; ++nb) {
        f32x4 acc[4][2] = {};
        for (int s = 0; s < 4; ++s) {
            s16x8 a[4], bw[2];
            #pragma unroll
            for (int mi = 0; mi < 4; ++mi)
                a[mi] = *(const s16x8*)&As[wm * 64 + mi * 16 + li][s * 32 + quad * 8];
            #pragma unroll
            for (int ni = 0; ni < 2; ++ni)
                bw[ni] = *(const s16x8*)&wq[(long)(nb * 128 + hh * 64 + wn * 32 + ni * 16 + li) * 128
                                            + s * 32 + quad * 8];
            #pragma unroll
            for (int mi = 0; mi < 4; ++mi)
                #pragma unroll
                for (int ni = 0; ni < 2; ++ni)
                    acc[mi][ni] = MFMA(a[mi], bw[ni], acc[mi][ni]);
        }
        if (nb == 2) __syncthreads();   // all As (A-operand) reads done before V^T overwrite
        #pragma unroll
        for (int mi = 0; mi < 4; ++mi)
            #pragma unroll
            for (int ni = 0; ni < 2; ++ni) {
                int lcol = wn * 32 + ni * 16 + li;          // 0..63
                int gcol = nb * 128 + hh * 64 + lcol;
                float bias = qkv_b[gcol];
                float scale = (nb == 0) ? 0.25f : 1.f;      // SCALE = 16^-0.5
                #pragma unroll
                for (int r = 0; r < 4; ++r) {
                    int trow = wm * 64 + mi * 16 + quad * 4 + r;
                    ushort val = f2b((acc[mi][ni][r] + bias) * scale);
                    if (nb == 0) {
                        qb[trow][lcol] = val;
                    } else if (nb == 1) {
                        kb[trow][lcol] = val;
                    } else {
                        int hl = lcol >> 4, dd = lcol & 15;
                        ((ushort*)As)[hl * 2176 + dd * 136 + trow] = val;  // V^T [hl][d][tok]
                    }
                }
            }
    }
    __syncthreads();
    // Phase C: attention (R5/R7-verified math), wave wv -> local head wv.
    const ushort* vtp = (const ushort*)As;
    {
        int hl = wv, hg = hh * 4 + wv;
        long bmb = (long)(cls * 8 + hg) * 16384;
        long ob = (long)wi * 16384 + hg * 2048;
        for (int qq = 0; qq < 4; ++qq) {
            int row0 = qq * 32;
            s16x4 qf0 = *(const s16x4*)&qb[row0 + li][hl * 16 + quad * 4];
            s16x4 qf1 = *(const s16x4*)&qb[row0 + 16 + li][hl * 16 + quad * 4];
            float ps0 = 0.f, ps1 = 0.f;
            uint pa0[8][2], pa1[8][2];
            #pragma unroll
            for (int mi = 0; mi < 8; ++mi) {
                s16x4 kf = *(const s16x4*)&kb[mi * 16 + li][hl * 16 + quad * 4];
                f32x4 z = {0.f, 0.f, 0.f, 0.f};
                f32x4 s0 = MFMA16(kf, qf0, z);
                f32x4 s1 = MFMA16(kf, qf1, z);
                s16x4 b0 = *(const s16x4*)&bm[bmb + (row0 + li) * 128 + mi * 16 + quad * 4];
                s16x4 b1 = *(const s16x4*)&bm[bmb + (row0 + 16 + li) * 128 + mi * 16 + quad * 4];
                float e0 = __expf(s0[0] + b2f((ushort)b0[0]));
                float e1 = __expf(s0[1] + b2f((ushort)b0[1]));
                float e2 = __expf(s0[2] + b2f((ushort)b0[2]));
                float e3 = __expf(s0[3] + b2f((ushort)b0[3]));
                ps0 += (e0 + e1) + (e2 + e3);
                pa0[mi][0] = (uint)f2b(e0) | ((uint)f2b(e1) << 16);
                pa0[mi][1] = (uint)f2b(e2) | ((uint)f2b(e3) << 16);
                float f0 = __expf(s1[0] + b2f((ushort)b1[0]));
                float f1 = __expf(s1[1] + b2f((ushort)b1[1]));
                float f2 = __expf(s1[2] + b2f((ushort)b1[2]));
                float f3 = __expf(s1[3] + b2f((ushort)b1[3]));
                ps1 += (f0 + f1) + (f2 + f3);
                pa1[mi][0] = (uint)f2b(f0) | ((uint)f2b(f1) << 16);
                pa1[mi][1] = (uint)f2b(f2) | ((uint)f2b(f3) << 16);
            }
            ps0 += __shfl_xor(ps0, 16); ps0 += __shfl_xor(ps0, 32);
            ps1 += __shfl_xor(ps1, 16); ps1 += __shfl_xor(ps1, 32);
            float inv0 = 1.f / ps0, inv1 = 1.f / ps1;
            f32x4 pc0 = {0.f, 0.f, 0.f, 0.f}, pc1 = {0.f, 0.f, 0.f, 0.f};
            #pragma unroll
            for (int mi = 0; mi < 8; ++mi) {
                s16x4 vf = *(const s16x4*)&vtp[hl * 2176 + li * 136 + mi * 16 + quad * 4];
                union { uint2 u; s16x4 v; } a0, a1;
                a0.u.x = pa0[mi][0]; a0.u.y = pa0[mi][1];
                a1.u.x = pa1[mi][0]; a1.u.y = pa1[mi][1];
                pc0 = MFMA16(a0.v, vf, pc0);
                pc1 = MFMA16(a1.v, vf, pc1);
            }
            #pragma unroll
            for (int r = 0; r < 4; ++r) {
                float oi0 = __shfl(inv0, quad * 4 + r);
                float oi1 = __shfl(inv1, quad * 4 + r);
                int i0 = row0 + quad * 4 + r;
                int i1 = row0 + 16 + quad * 4 + r;
                obuf[ob + (long)i0 * 16 + li] = f2b(pc0[r] * oi0);
                obuf[ob + (long)i1 * 16 + li] = f2b(pc1[r] * oi1);
            }
        }
    }
}

// ---------------------------------------------------------------------------
// K45 (R11): untouched proven floor (103.3-104.1us): 64-token tile,
// 1024x256, x1 in x1t LDS (VGPR 96, no spill), 12 barriers, LDS 52.7KB.
// ao = compact O buffer [wi][head][tok][16].
// ---------------------------------------------------------------------------
__global__ __launch_bounds__(256) void k45(
    const ushort* __restrict__ ao, const ushort* __restrict__ wp,
    const float* __restrict__ proj_b, const float* __restrict__ x,
    const float* __restrict__ g2, const float* __restrict__ be2,
    const ushort* __restrict__ wf1, const float* __restrict__ fc1_b,
    const ushort* __restrict__ wf2, const float* __restrict__ fc2_b,
    float* __restrict__ out)
{
    __shared__ __align__(16) ushort As[64][132];    // ao tile, later xs (LN2 out)
    __shared__ __align__(16) ushort x1t[64][132];   // x1 (bf16)
    __shared__ __align__(16) ushort hs[64][132];    // gelu(h) chunk
    __shared__ float redS[4][64];
    __shared__ float redQ[4][64];
    int tid = threadIdx.x;
    int b = blockIdx.x;
    int wi = b >> 1, half64 = b & 1;
    int wd = (wi >> 6) & 3, wh = (wi >> 3) & 7, ww = wi & 7;
    int bb = wi >> 8;
    long aob = (long)wi * 16384;
    int tok0 = half64 * 64;
    #pragma unroll
    for (int i = 0; i < 4; ++i) {
        int slot = tid + i * 256;               // 0..1023
        int row = slot & 63, hsl = slot >> 6;   // hsl = head*2 + (d-half)
        *(uint4*)&As[row][hsl * 8] =
            *(const uint4*)&ao[aob + (hsl >> 1) * 2048 + (long)(tok0 + row) * 16 + (hsl & 1) * 8];
    }
    __syncthreads();
    int wv = tid >> 6, lane = tid & 63, li = lane & 15, quad = lane >> 4;
    int wm = wv >> 1, wn = wv & 1;
    f32x4 acc[2][4] = {};
    for (int s = 0; s < 4; ++s) {
        s16x8 a[2], bw[4];
        #pragma unroll
        for (int mi = 0; mi < 2; ++mi)
            a[mi] = *(const s16x8*)&As[wm * 32 + mi * 16 + li][s * 32 + quad * 8];
        #pragma unroll
        for (int ni = 0; ni < 4; ++ni)
            bw[ni] = *(const s16x8*)&wp[(long)(wn * 64 + ni * 16 + li) * 128 + s * 32 + quad * 8];
        #pragma unroll
        for (int mi = 0; mi < 2; ++mi)
            #pragma unroll
            for (int ni = 0; ni < 4; ++ni)
                acc[mi][ni] = MFMA(a[mi], bw[ni], acc[mi][ni]);
    }
    // epilogue: residual add (f32 x) -> x1t (bf16)
    #pragma unroll
    for (int mi = 0; mi < 2; ++mi) {
        #pragma unroll
        for (int r = 0; r < 4; ++r) {
            int lrow = wm * 32 + mi * 16 + quad * 4 + r;
            int t = half64 * 64 + lrow;
            int td = t >> 6, th = (t >> 3) & 7, tw = t & 7;
            int d = (wd * 2 + td + 1) & 7, h = (wh * 8 + th + 4) & 63, w = (ww * 8 + tw + 4) & 63;
            long di = (((long)((bb * 8 + d) * 64 + h)) * 64 + w) * 128;
            #pragma unroll
            for (int ni = 0; ni < 4; ++ni) {
                int col = wn * 64 + ni * 16 + li;
                x1t[lrow][col] = f2b(acc[mi][ni][r] + proj_b[col] + x[di + col]);
            }
        }
    }
    __syncthreads();
    {   // LN2 from x1t -> xs (reuse As)
        int token = tid & 63, part = tid >> 6;
        float vals[32];
        float s = 0.f, q = 0.f;
        #pragma unroll
        for (int i = 0; i < 4; ++i) {
            uint4 u = *(const uint4*)&x1t[token][part * 32 + i * 8];
            const ushort* p = (const ushort*)&u;
            #pragma unroll
            for (int j = 0; j < 8; ++j) { float f = b2f(p[j]); vals[i * 8 + j] = f; s += f; q += f * f; }
        }
        redS[part][token] = s; redQ[part][token] = q;
        __syncthreads();
        float st = 0.f, qt = 0.f;
        #pragma unroll
        for (int p2 = 0; p2 < 4; ++p2) { st += redS[p2][token]; qt += redQ[p2][token]; }
        float mean = st * (1.f / 128.f);
        float rstd = rsqrtf(qt * (1.f / 128.f) - mean * mean + 1e-5f);
        #pragma unroll
        for (int i = 0; i < 4; ++i) {
            ushort packed[8];
            #pragma unroll
            for (int j = 0; j < 8; ++j) {
                int c = part * 32 + i * 8 + j;
                packed[j] = f2b((vals[i * 8 + j] - mean) * rstd * g2[c] + be2[c]);
            }
            *(uint4*)&As[token][part * 32 + i * 8] = *(uint4*)packed;
        }
    }
    __syncthreads();
    f32x4 yacc[2][4] = {};
    for (int hc = 0; hc < 4; ++hc) {
        f32x4 hacc[2][4] = {};
        #pragma unroll
        for (int kk = 0; kk < 4; ++kk) {
            s16x8 a[2], bw[4];
            #pragma unroll
            for (int mi = 0; mi < 2; ++mi)
                a[mi] = *(const s16x8*)&As[wm * 32 + mi * 16 + li][kk * 32 + quad * 8];
            #pragma unroll
            for (int ni = 0; ni < 4; ++ni)
                bw[ni] = *(const s16x8*)&wf1[(long)(hc * 128 + wn * 64 + ni * 16 + li) * 128
                                             + kk * 32 + quad * 8];
            #pragma unroll
            for (int mi = 0; mi < 2; ++mi)
                #pragma unroll
                for (int ni = 0; ni < 4; ++ni)
                    hacc[mi][ni] = MFMA(a[mi], bw[ni], hacc[mi][ni]);
        }
        #pragma unroll
        for (int mi = 0; mi < 2; ++mi)
            #pragma unroll
            for (int ni = 0; ni < 4; ++ni) {
                int col = wn * 64 + ni * 16 + li;
                float bbv = fc1_b[hc * 128 + col];
                #pragma unroll
                for (int r = 0; r < 4; ++r) {
                    int row = wm * 32 + mi * 16 + quad * 4 + r;
                    hs[row][col] = f2b(gelu_tanh(hacc[mi][ni][r] + bbv));
                }
            }
        __syncthreads();
        #pragma unroll
        for (int kk = 0; kk < 4; ++kk) {
            s16x8 a[2], bw[4];
            #pragma unroll
            for (int mi = 0; mi < 2; ++mi)
                a[mi] = *(const s16x8*)&hs[wm * 32 + mi * 16 + li][kk * 32 + quad * 8];
            #pragma unroll
            for (int ni = 0; ni < 4; ++ni)
                bw[ni] = *(const s16x8*)&wf2[(long)(wn * 64 + ni * 16 + li) * 512
                                             + hc * 128 + kk * 32 + quad * 8];
            #pragma unroll
            for (int mi = 0; mi < 2; ++mi)
                #pragma unroll
                for (int ni = 0; ni < 4; ++ni)
                    yacc[mi][ni] = MFMA(a[mi], bw[ni], yacc[mi][ni]);
        }
        __syncthreads();
    }
    #pragma unroll
    for (int mi = 0; mi < 2; ++mi) {
        #pragma unroll
        for (int r = 0; r < 4; ++r) {
            int lrow = wm * 32 + mi * 16 + quad * 4 + r;
            int t = half64 * 64 + lrow;
            int td = t >> 6, th = (t >> 3) & 7, tw = t & 7;
            int d = (wd * 2 + td + 1) & 7, h = (wh * 8 + th + 4) & 63, w = (ww * 8 + tw + 4) & 63;
            long di = (((long)((bb * 8 + d) * 64 + h)) * 64 + w) * 128;
            #pragma unroll
            for (int ni = 0; ni < 4; ++ni) {
                int col = wn * 64 + ni * 16 + li;
                out[di + col] = b2f(x1t[lrow][col]) + yacc[mi][ni][r] + fc2_b[col];
            }
        }
    }
}

// ---------------------------------------------------------------------------
// ws layout (~18.4MB):
//   [0 .. 16MB): obuf = attn-out, [wi][head][tok][16] (window stride 16384).
//   tail: wq 96KB | wp 32KB | wf 256KB | bm 2MB (contiguous after obuf;
//   k0 writes wq|wp|wf via one unified index).
// d_out holds ONLY the final f32 output (no scratch -> no races).
// ---------------------------------------------------------------------------
extern "C" void kernel_launch(void* const* d_in, const int* in_sizes, int n_in,
                              void* d_out, int out_size, void* d_ws, size_t ws_size,
                              hipStream_t stream)
{
    (void)in_sizes; (void)n_in; (void)out_size; (void)ws_size;
    const float* x      = (const float*)d_in[0];
    const float* qkv_w  = (const float*)d_in[1];
    const float* qkv_b  = (const float*)d_in[2];
    const float* proj_w = (const float*)d_in[3];
    const float* proj_b = (const float*)d_in[4];
    const float* rpb    = (const float*)d_in[5];
    const float* ln1_g  = (const float*)d_in[6];
    const float* ln1_b  = (const float*)d_in[7];
    const float* ln2_g  = (const float*)d_in[8];
    const float* ln2_b  = (const float*)d_in[9];
    const float* fc1_w  = (const float*)d_in[10];
    const float* fc1_b  = (const float*)d_in[11];
    const float* fc2_w  = (const float*)d_in[12];
    const float* fc2_b  = (const float*)d_in[13];
    float* out = (float*)d_out;

    ushort* obuf = (ushort*)d_ws;                       // 16 MB
    ushort* wq   = (ushort*)((char*)d_ws + 16777216);   // 49152 elems
    ushort* wp   = wq + 49152;                          // 16384
    ushort* wf   = wp + 16384;                          // 131072
    ushort* bm   = wf + 131072;                         // 1048576

    hipLaunchKernelGGL(k0_prep, dim3(704), dim3(256), 0, stream,
                       qkv_w, proj_w, fc1_w, fc2_w, rpb, wq, wp, wf, bm);
    hipLaunchKernelGGL(k23, dim3(1024), dim3(256), 0, stream,
                       x, ln1_g, ln1_b, wq, qkv_b, bm, obuf);
    hipLaunchKernelGGL(k45, dim3(1024), dim3(256), 0, stream,
                       obuf, wp, proj_b, x, ln2_g, ln2_b,
                       wf, fc1_b, wf + 65536, fc2_b, out);
}